// Round 1
// baseline (1295.519 us; speedup 1.0000x reference)
//
#include <hip/hip_runtime.h>
#include <math.h>

#define NE 8          // experts
#define PI_F 3.14159265358979323846f

// ---------------- Router: probs[p][e] per layer (data-independent) ----------
__global__ __launch_bounds__(64) void router_kernel(
    const float* __restrict__ rw,   // [16][52]
    const float* __restrict__ rb,   // [16]
    const float* __restrict__ rlw,  // [8][16]
    const float* __restrict__ rlb,  // [8]
    float* __restrict__ probs)      // [256][8]
{
    int p = blockIdx.x;           // patch 0..255
    int lane = threadIdx.x;       // pixel 0..63
    int py = p >> 4, px = p & 15;
    int i = lane >> 3, j = lane & 7;
    int y = py * 8 + i, x = px * 8 + j;

    float base0 = (x + 0.5f) / 128.0f;  // Gx
    float base1 = (y + 0.5f) / 128.0f;  // Gy
    float base2 = (j + 0.5f) / 8.0f;    // Lx
    float base3 = (i + 0.5f) / 8.0f;    // Ly

    float coord[52];
    coord[0] = base0; coord[1] = base1; coord[2] = base2; coord[3] = base3;
    int c = 4;
    #pragma unroll
    for (int f = 0; f < 6; ++f) {
        float w = PI_F * (float)(1 << f);
        coord[c+0] = sinf(w * base0);
        coord[c+1] = sinf(w * base1);
        coord[c+2] = sinf(w * base2);
        coord[c+3] = sinf(w * base3);
        coord[c+4] = cosf(w * base0);
        coord[c+5] = cosf(w * base1);
        coord[c+6] = cosf(w * base2);
        coord[c+7] = cosf(w * base3);
        c += 8;
    }

    // per-pixel router hidden activations, relu, then mean over 64 pixels
    float z[16];
    #pragma unroll
    for (int r = 0; r < 16; ++r) {
        float a = rb[r];
        #pragma unroll
        for (int cc = 0; cc < 52; ++cc) a += rw[r*52 + cc] * coord[cc];
        z[r] = fmaxf(a, 0.0f);
    }
    #pragma unroll
    for (int r = 0; r < 16; ++r) {
        float v = z[r];
        #pragma unroll
        for (int off = 32; off > 0; off >>= 1) v += __shfl_xor(v, off);
        z[r] = v * (1.0f / 64.0f);
    }

    // lanes replicate per group of 8: e = lane&7
    int e = lane & 7;
    float logit = rlb[e];
    #pragma unroll
    for (int r = 0; r < 16; ++r) logit += rlw[e*16 + r] * z[r];

    float m = logit;
    #pragma unroll
    for (int off = 4; off > 0; off >>= 1) m = fmaxf(m, __shfl_xor(m, off));
    float ex = expf(logit - m);
    float s = ex;
    #pragma unroll
    for (int off = 4; off > 0; off >>= 1) s += __shfl_xor(s, off);
    float pr = ex / s;
    pr = (pr >= 0.05f) ? pr : 0.0f;
    float s2 = pr;
    #pragma unroll
    for (int off = 4; off > 0; off >>= 1) s2 += __shfl_xor(s2, off);
    pr = pr / (s2 + 1e-9f);
    if (lane < 8) probs[p*8 + lane] = pr;
}

// ---------------- Per-layer patch-wise expert conv + weighted combine -------
// Block = one (batch b, patch p). 256 threads = 32 oc-groups x 8 rows.
// Each thread: OPT consecutive output channels (all one expert) x 8 pixels.
template<int CIN, int COUT, bool NCHW_IN>
__global__ __launch_bounds__(256) void pce_conv(
    const float* __restrict__ Xin,
    const float* __restrict__ ew,    // [NE*COUT][CIN][3][3]
    const float* __restrict__ eb,    // [NE*COUT]
    const float* __restrict__ probs, // [256][8]
    float* __restrict__ Xout)        // [B][256][COUT][64]
{
    constexpr int OPT = (NE * COUT) / 32;   // oc per thread
    int bx = blockIdx.x;
    int b = bx >> 8, p = bx & 255;
    int py = p >> 4, px = p & 15;
    int tid = threadIdx.x;

    __shared__ float sp[CIN][10][10];   // zero-padded patch
    __shared__ float so[COUT * 64];     // combined output

    for (int t = tid; t < CIN * 100; t += 256) ((float*)sp)[t] = 0.0f;
    for (int t = tid; t < COUT * 64; t += 256) so[t] = 0.0f;
    __syncthreads();

    for (int t = tid; t < CIN * 64; t += 256) {
        int cin = t >> 6, pix = t & 63, i = pix >> 3, j = pix & 7;
        float v;
        if (NCHW_IN)
            v = Xin[((b * CIN + cin) * 128 + (py * 8 + i)) * 128 + (px * 8 + j)];
        else
            v = Xin[((b * 256 + p) * CIN + cin) * 64 + pix];
        sp[cin][i + 1][j + 1] = v;
    }
    __syncthreads();

    int ocg = tid >> 3, row = tid & 7;
    int oc0 = ocg * OPT;
    int e = oc0 / COUT;                  // OPT divides COUT -> single expert
    float pe = probs[p * 8 + e];
    if (pe > 0.0f) {
        float acc[OPT][8];
        #pragma unroll
        for (int u = 0; u < OPT; ++u)
            #pragma unroll
            for (int j = 0; j < 8; ++j) acc[u][j] = 0.0f;

        for (int cin = 0; cin < CIN; ++cin) {
            float win[3][10];
            #pragma unroll
            for (int r = 0; r < 3; ++r)
                #pragma unroll
                for (int cc = 0; cc < 10; ++cc)
                    win[r][cc] = sp[cin][row + r][cc];

            #pragma unroll
            for (int u = 0; u < OPT; ++u) {
                const float* wp = ew + ((size_t)(oc0 + u) * CIN + cin) * 9;
                float w0 = wp[0], w1 = wp[1], w2 = wp[2];
                float w3 = wp[3], w4 = wp[4], w5 = wp[5];
                float w6 = wp[6], w7 = wp[7], w8 = wp[8];
                #pragma unroll
                for (int j = 0; j < 8; ++j) {
                    acc[u][j] += w0 * win[0][j] + w1 * win[0][j+1] + w2 * win[0][j+2]
                               + w3 * win[1][j] + w4 * win[1][j+1] + w5 * win[1][j+2]
                               + w6 * win[2][j] + w7 * win[2][j+1] + w8 * win[2][j+2];
                }
            }
        }
        #pragma unroll
        for (int u = 0; u < OPT; ++u) {
            float bias = eb[oc0 + u];
            int cout = (oc0 + u) % COUT;
            #pragma unroll
            for (int j = 0; j < 8; ++j) {
                float v = fmaxf(acc[u][j] + bias, 0.0f) * pe;
                atomicAdd(&so[cout * 64 + row * 8 + j], v);
            }
        }
    }
    __syncthreads();

    float* op = Xout + ((size_t)(b * 256 + p) * COUT) * 64;
    for (int t = tid; t < COUT * 64; t += 256) op[t] = so[t];
}

// ---------------- Fused 16x16 mean-pool + FC --------------------------------
__global__ __launch_bounds__(256) void pool_fc(
    const float* __restrict__ Xp,   // [16][256][32][64]
    const float* __restrict__ fcw,  // [100][2048]
    const float* __restrict__ fcb,  // [100]
    float* __restrict__ out)        // [16][100]
{
    int b = blockIdx.x;
    __shared__ float pooled[2048];  // [c][oy][ox] = c*64 + oy*8 + ox
    for (int idx = threadIdx.x; idx < 2048; idx += 256) {
        int cch = idx >> 6, oy = (idx >> 3) & 7, ox = idx & 7;
        float s = 0.0f;
        #pragma unroll
        for (int dy = 0; dy < 2; ++dy)
            #pragma unroll
            for (int dx = 0; dx < 2; ++dx) {
                int p = (2 * oy + dy) * 16 + (2 * ox + dx);
                const float* q = Xp + ((size_t)(b * 256 + p) * 32 + cch) * 64;
                for (int k = 0; k < 64; ++k) s += q[k];
            }
        pooled[idx] = s * (1.0f / 256.0f);
    }
    __syncthreads();

    int wave = threadIdx.x >> 6, lane = threadIdx.x & 63;
    for (int cls = wave; cls < 100; cls += 4) {
        float a = 0.0f;
        #pragma unroll
        for (int r = 0; r < 32; ++r)
            a += pooled[r * 64 + lane] * fcw[(size_t)cls * 2048 + r * 64 + lane];
        #pragma unroll
        for (int off = 32; off > 0; off >>= 1) a += __shfl_down(a, off);
        if (lane == 0) out[b * 100 + cls] = a + fcb[cls];
    }
}

// ---------------- Launch ----------------------------------------------------
extern "C" void kernel_launch(void* const* d_in, const int* in_sizes, int n_in,
                              void* d_out, int out_size, void* d_ws, size_t ws_size,
                              hipStream_t stream) {
    const float* X = (const float*)d_in[0];
    const float* ew[4]; const float* eb[4];
    const float* rw[4]; const float* rb[4];
    const float* rlw[4]; const float* rlb[4];
    for (int l = 0; l < 4; ++l) {
        ew[l]  = (const float*)d_in[1 + 6*l + 0];
        eb[l]  = (const float*)d_in[1 + 6*l + 1];
        rw[l]  = (const float*)d_in[1 + 6*l + 2];
        rb[l]  = (const float*)d_in[1 + 6*l + 3];
        rlw[l] = (const float*)d_in[1 + 6*l + 4];
        rlb[l] = (const float*)d_in[1 + 6*l + 5];
    }
    const float* fcw = (const float*)d_in[25];
    const float* fcb = (const float*)d_in[26];

    float* probs = (float*)d_ws;                         // 4 * 256 * 8 floats
    float* buf0 = (float*)((char*)d_ws + 32768);         // up to [16][256][16][64]
    float* buf1 = buf0 + (size_t)16 * 256 * 16 * 64;     // up to [16][256][32][64]

    for (int l = 0; l < 4; ++l)
        router_kernel<<<256, 64, 0, stream>>>(rw[l], rb[l], rlw[l], rlb[l],
                                              probs + l * 256 * 8);

    pce_conv<3, 8, true ><<<4096, 256, 0, stream>>>(X,    ew[0], eb[0], probs + 0*2048, buf0);
    pce_conv<8, 16, false><<<4096, 256, 0, stream>>>(buf0, ew[1], eb[1], probs + 1*2048, buf1);
    pce_conv<16,16, false><<<4096, 256, 0, stream>>>(buf1, ew[2], eb[2], probs + 2*2048, buf0);
    pce_conv<16,32, false><<<4096, 256, 0, stream>>>(buf0, ew[3], eb[3], probs + 3*2048, buf1);

    pool_fc<<<16, 256, 0, stream>>>(buf1, fcw, fcb, (float*)d_out);
}

// Round 2
// 766.883 us; speedup vs baseline: 1.6893x; 1.6893x over previous
//
#include <hip/hip_runtime.h>
#include <math.h>

#define NE 8
#define PI_F 3.14159265358979323846f

// ---------------- Router: probs[p][e] per layer (data-independent) ----------
__global__ __launch_bounds__(64) void router_kernel(
    const float* __restrict__ rw,   // [16][52]
    const float* __restrict__ rb,   // [16]
    const float* __restrict__ rlw,  // [8][16]
    const float* __restrict__ rlb,  // [8]
    float* __restrict__ probs)      // [256][8]
{
    int p = blockIdx.x;
    int lane = threadIdx.x;
    int py = p >> 4, px = p & 15;
    int i = lane >> 3, j = lane & 7;
    int y = py * 8 + i, x = px * 8 + j;

    float base0 = (x + 0.5f) / 128.0f;
    float base1 = (y + 0.5f) / 128.0f;
    float base2 = (j + 0.5f) / 8.0f;
    float base3 = (i + 0.5f) / 8.0f;

    float coord[52];
    coord[0] = base0; coord[1] = base1; coord[2] = base2; coord[3] = base3;
    int c = 4;
    #pragma unroll
    for (int f = 0; f < 6; ++f) {
        float w = PI_F * (float)(1 << f);
        coord[c+0] = sinf(w * base0);
        coord[c+1] = sinf(w * base1);
        coord[c+2] = sinf(w * base2);
        coord[c+3] = sinf(w * base3);
        coord[c+4] = cosf(w * base0);
        coord[c+5] = cosf(w * base1);
        coord[c+6] = cosf(w * base2);
        coord[c+7] = cosf(w * base3);
        c += 8;
    }

    float z[16];
    #pragma unroll
    for (int r = 0; r < 16; ++r) {
        float a = rb[r];
        #pragma unroll
        for (int cc = 0; cc < 52; ++cc) a += rw[r*52 + cc] * coord[cc];
        z[r] = fmaxf(a, 0.0f);
    }
    #pragma unroll
    for (int r = 0; r < 16; ++r) {
        float v = z[r];
        #pragma unroll
        for (int off = 32; off > 0; off >>= 1) v += __shfl_xor(v, off);
        z[r] = v * (1.0f / 64.0f);
    }

    int e = lane & 7;
    float logit = rlb[e];
    #pragma unroll
    for (int r = 0; r < 16; ++r) logit += rlw[e*16 + r] * z[r];

    float m = logit;
    #pragma unroll
    for (int off = 4; off > 0; off >>= 1) m = fmaxf(m, __shfl_xor(m, off));
    float ex = expf(logit - m);
    float s = ex;
    #pragma unroll
    for (int off = 4; off > 0; off >>= 1) s += __shfl_xor(s, off);
    float pr = ex / s;
    pr = (pr >= 0.05f) ? pr : 0.0f;
    float s2 = pr;
    #pragma unroll
    for (int off = 4; off > 0; off >>= 1) s2 += __shfl_xor(s2, off);
    pr = pr / (s2 + 1e-9f);
    if (lane < 8) probs[p*8 + lane] = pr;
}

// ---------------- Expert-chunk conv accumulate ------------------------------
// Processes KC experts (KC=1 or 2) for one thread's (cout, PPT pixels),
// adding pe * relu(conv_e + bias) into fin[].
template<int CIN, int COUT, int PPT, int KC>
__device__ __forceinline__ void conv_chunk(
    const float (*sp)[10][12], const float* __restrict__ ew,
    const float* __restrict__ eb,
    const int* e_ids, const float* e_ps,
    int cout, int row, int col0, float* fin)
{
    float acc[KC][PPT];
    #pragma unroll
    for (int u = 0; u < KC; ++u)
        #pragma unroll
        for (int q = 0; q < PPT; ++q) acc[u][q] = 0.0f;

    const float* wb[KC];
    #pragma unroll
    for (int u = 0; u < KC; ++u)
        wb[u] = ew + (size_t)(e_ids[u] * COUT + cout) * CIN * 9;

    for (int cin = 0; cin < CIN; ++cin) {
        float win[3][PPT + 2];
        #pragma unroll
        for (int r = 0; r < 3; ++r)
            #pragma unroll
            for (int cc = 0; cc < PPT + 2; ++cc)
                win[r][cc] = sp[cin][row + r][col0 + cc];

        #pragma unroll
        for (int u = 0; u < KC; ++u) {
            const float* wp = wb[u] + cin * 9;
            #pragma unroll
            for (int r = 0; r < 3; ++r) {
                float w0 = wp[r*3+0], w1 = wp[r*3+1], w2 = wp[r*3+2];
                #pragma unroll
                for (int q = 0; q < PPT; ++q)
                    acc[u][q] = fmaf(w0, win[r][q],
                                fmaf(w1, win[r][q+1],
                                fmaf(w2, win[r][q+2], acc[u][q])));
            }
        }
    }
    #pragma unroll
    for (int u = 0; u < KC; ++u) {
        float bias = eb[e_ids[u] * COUT + cout];
        float pe = e_ps[u];
        #pragma unroll
        for (int q = 0; q < PPT; ++q)
            fin[q] += pe * fmaxf(acc[u][q] + bias, 0.0f);
    }
}

// ---------------- Per-layer patch conv, active-experts-only -----------------
// Block = one (b, p). 256 threads partition the COUT*64 outputs:
// thread owns PPT consecutive pixels of one cout; loops over active experts.
template<int CIN, int COUT, bool NCHW_IN>
__global__ __launch_bounds__(256) void pce_conv(
    const float* __restrict__ Xin,
    const float* __restrict__ ew,    // [NE*COUT][CIN][3][3]
    const float* __restrict__ eb,    // [NE*COUT]
    const float* __restrict__ probs, // [256][8]
    float* __restrict__ Xout)        // [B][256][COUT][64]
{
    constexpr int PPT = (COUT * 64) / 256;   // 2, 4, 8
    constexpr int TPC = 64 / PPT;            // threads per cout
    int bx = blockIdx.x;
    int b = bx >> 8, p = bx & 255;
    int py = p >> 4, px = p & 15;
    int tid = threadIdx.x;

    __shared__ float sp[CIN][10][12];   // zero-padded patch, stride-12 rows
    __shared__ float se[8];
    __shared__ int   sk[8];
    __shared__ int   skn;

    for (int t = tid; t < CIN * 120; t += 256) ((float*)sp)[t] = 0.0f;
    if (tid < 8) se[tid] = probs[p * 8 + tid];
    __syncthreads();

    if (tid == 0) {
        int n = 0;
        for (int e = 0; e < 8; ++e) if (se[e] > 0.0f) { sk[n] = e; ++n; }
        skn = n;
    }
    for (int t = tid; t < CIN * 64; t += 256) {
        int cin = t >> 6, pix = t & 63, i = pix >> 3, j = pix & 7;
        float v;
        if (NCHW_IN)
            v = Xin[((b * CIN + cin) * 128 + (py * 8 + i)) * 128 + (px * 8 + j)];
        else
            v = Xin[((b * 256 + p) * CIN + cin) * 64 + pix];
        sp[cin][i + 1][j + 1] = v;
    }
    __syncthreads();

    int cout = tid / TPC, sub = tid % TPC;
    int pix0 = sub * PPT;
    int row = pix0 >> 3, col0 = pix0 & 7;
    int k = skn;

    float fin[PPT];
    #pragma unroll
    for (int q = 0; q < PPT; ++q) fin[q] = 0.0f;

    int ei = 0;
    for (; ei + 1 < k; ei += 2) {
        int   eid[2] = { sk[ei], sk[ei + 1] };
        float eps[2] = { se[eid[0]], se[eid[1]] };
        conv_chunk<CIN, COUT, PPT, 2>(sp, ew, eb, eid, eps, cout, row, col0, fin);
    }
    if (ei < k) {
        int   eid[1] = { sk[ei] };
        float eps[1] = { se[eid[0]] };
        conv_chunk<CIN, COUT, PPT, 1>(sp, ew, eb, eid, eps, cout, row, col0, fin);
    }

    float* op = Xout + ((size_t)(b * 256 + p) * COUT + cout) * 64 + pix0;
    #pragma unroll
    for (int q = 0; q < PPT; ++q) op[q] = fin[q];
}

// ---------------- Fused 16x16 mean-pool + FC --------------------------------
__global__ __launch_bounds__(256) void pool_fc(
    const float* __restrict__ Xp,   // [16][256][32][64]
    const float* __restrict__ fcw,  // [100][2048]
    const float* __restrict__ fcb,  // [100]
    float* __restrict__ out)        // [16][100]
{
    int b = blockIdx.x;
    __shared__ float pooled[2048];
    for (int idx = threadIdx.x; idx < 2048; idx += 256) {
        int cch = idx >> 6, oy = (idx >> 3) & 7, ox = idx & 7;
        float s = 0.0f;
        #pragma unroll
        for (int dy = 0; dy < 2; ++dy)
            #pragma unroll
            for (int dx = 0; dx < 2; ++dx) {
                int p = (2 * oy + dy) * 16 + (2 * ox + dx);
                const float* q = Xp + ((size_t)(b * 256 + p) * 32 + cch) * 64;
                for (int kk = 0; kk < 64; ++kk) s += q[kk];
            }
        pooled[idx] = s * (1.0f / 256.0f);
    }
    __syncthreads();

    int wave = threadIdx.x >> 6, lane = threadIdx.x & 63;
    for (int cls = wave; cls < 100; cls += 4) {
        float a = 0.0f;
        #pragma unroll
        for (int r = 0; r < 32; ++r)
            a += pooled[r * 64 + lane] * fcw[(size_t)cls * 2048 + r * 64 + lane];
        #pragma unroll
        for (int off = 32; off > 0; off >>= 1) a += __shfl_down(a, off);
        if (lane == 0) out[b * 100 + cls] = a + fcb[cls];
    }
}

// ---------------- Launch ----------------------------------------------------
extern "C" void kernel_launch(void* const* d_in, const int* in_sizes, int n_in,
                              void* d_out, int out_size, void* d_ws, size_t ws_size,
                              hipStream_t stream) {
    const float* X = (const float*)d_in[0];
    const float* ew[4]; const float* eb[4];
    const float* rw[4]; const float* rb[4];
    const float* rlw[4]; const float* rlb[4];
    for (int l = 0; l < 4; ++l) {
        ew[l]  = (const float*)d_in[1 + 6*l + 0];
        eb[l]  = (const float*)d_in[1 + 6*l + 1];
        rw[l]  = (const float*)d_in[1 + 6*l + 2];
        rb[l]  = (const float*)d_in[1 + 6*l + 3];
        rlw[l] = (const float*)d_in[1 + 6*l + 4];
        rlb[l] = (const float*)d_in[1 + 6*l + 5];
    }
    const float* fcw = (const float*)d_in[25];
    const float* fcb = (const float*)d_in[26];

    float* probs = (float*)d_ws;                         // 4 * 256 * 8 floats
    float* buf0 = (float*)((char*)d_ws + 32768);         // [16][256][16][64] max
    float* buf1 = buf0 + (size_t)16 * 256 * 16 * 64;     // [16][256][32][64] max

    for (int l = 0; l < 4; ++l)
        router_kernel<<<256, 64, 0, stream>>>(rw[l], rb[l], rlw[l], rlb[l],
                                              probs + l * 256 * 8);

    pce_conv<3, 8, true ><<<4096, 256, 0, stream>>>(X,    ew[0], eb[0], probs + 0*2048, buf0);
    pce_conv<8, 16, false><<<4096, 256, 0, stream>>>(buf0, ew[1], eb[1], probs + 1*2048, buf1);
    pce_conv<16,16, false><<<4096, 256, 0, stream>>>(buf1, ew[2], eb[2], probs + 2*2048, buf0);
    pce_conv<16,32, false><<<4096, 256, 0, stream>>>(buf0, ew[3], eb[3], probs + 3*2048, buf1);

    pool_fc<<<16, 256, 0, stream>>>(buf1, fcw, fcb, (float*)d_out);
}

// Round 3
// 396.782 us; speedup vs baseline: 3.2651x; 1.9328x over previous
//
#include <hip/hip_runtime.h>
#include <math.h>

#define NE 8
#define PI_F 3.14159265358979323846f

typedef _Float16 half8 __attribute__((ext_vector_type(8)));
typedef float f32x4 __attribute__((ext_vector_type(4)));

// ---------------- Router: probs[p][e] per layer (data-independent) ----------
__global__ __launch_bounds__(64) void router_kernel(
    const float* __restrict__ rw, const float* __restrict__ rb,
    const float* __restrict__ rlw, const float* __restrict__ rlb,
    float* __restrict__ probs)
{
    int p = blockIdx.x;
    int lane = threadIdx.x;
    int py = p >> 4, px = p & 15;
    int i = lane >> 3, j = lane & 7;
    int y = py * 8 + i, x = px * 8 + j;

    float base0 = (x + 0.5f) / 128.0f;
    float base1 = (y + 0.5f) / 128.0f;
    float base2 = (j + 0.5f) / 8.0f;
    float base3 = (i + 0.5f) / 8.0f;

    float coord[52];
    coord[0] = base0; coord[1] = base1; coord[2] = base2; coord[3] = base3;
    int c = 4;
    #pragma unroll
    for (int f = 0; f < 6; ++f) {
        float w = PI_F * (float)(1 << f);
        coord[c+0] = sinf(w * base0); coord[c+1] = sinf(w * base1);
        coord[c+2] = sinf(w * base2); coord[c+3] = sinf(w * base3);
        coord[c+4] = cosf(w * base0); coord[c+5] = cosf(w * base1);
        coord[c+6] = cosf(w * base2); coord[c+7] = cosf(w * base3);
        c += 8;
    }

    float z[16];
    #pragma unroll
    for (int r = 0; r < 16; ++r) {
        float a = rb[r];
        #pragma unroll
        for (int cc = 0; cc < 52; ++cc) a += rw[r*52 + cc] * coord[cc];
        z[r] = fmaxf(a, 0.0f);
    }
    #pragma unroll
    for (int r = 0; r < 16; ++r) {
        float v = z[r];
        #pragma unroll
        for (int off = 32; off > 0; off >>= 1) v += __shfl_xor(v, off);
        z[r] = v * (1.0f / 64.0f);
    }

    int e = lane & 7;
    float logit = rlb[e];
    #pragma unroll
    for (int r = 0; r < 16; ++r) logit += rlw[e*16 + r] * z[r];

    float m = logit;
    #pragma unroll
    for (int off = 4; off > 0; off >>= 1) m = fmaxf(m, __shfl_xor(m, off));
    float ex = expf(logit - m);
    float s = ex;
    #pragma unroll
    for (int off = 4; off > 0; off >>= 1) s += __shfl_xor(s, off);
    float pr = ex / s;
    pr = (pr >= 0.05f) ? pr : 0.0f;
    float s2 = pr;
    #pragma unroll
    for (int off = 4; off > 0; off >>= 1) s2 += __shfl_xor(s2, off);
    pr = pr / (s2 + 1e-9f);
    if (lane < 8) probs[p*8 + lane] = pr;
}

// ---------------- Weight prep: fp16 A-fragments, lane-swizzled --------------
// k-map: k = cin*12 + (dy*3+dx), slots 9..11 zero. Fragment (mt,ks,lane,j):
// m = mt*16 + (lane&15), k = ks*32 + (lane>>4)*8 + j.
template<int CIN, int COUT, int KS>
__global__ __launch_bounds__(256) void prep_w(
    const float* __restrict__ ew, unsigned short* __restrict__ wA)
{
    constexpr int MT = (NE * COUT) / 16;
    int idx = blockIdx.x * 256 + threadIdx.x;
    int total = MT * KS * 64 * 8;
    if (idx >= total) return;
    int j    = idx & 7;
    int lane = (idx >> 3) & 63;
    int t2   = idx >> 9;
    int ks   = t2 % KS;
    int mt   = t2 / KS;
    int m = mt * 16 + (lane & 15);
    int k = ks * 32 + (lane >> 4) * 8 + j;
    int cin = k / 12, r = k % 12;
    float val = 0.0f;
    if (cin < CIN && r < 9) val = ew[((size_t)m * CIN + cin) * 9 + r];
    _Float16 h = (_Float16)val;
    union { _Float16 h1; unsigned short u; } cv; cv.h1 = h;
    wA[idx] = cv.u;
}

__device__ __forceinline__ unsigned int pack2(_Float16 a, _Float16 b) {
    union { _Float16 h2[2]; unsigned int u; } x;
    x.h2[0] = a; x.h2[1] = b; return x.u;
}

// ---------------- MFMA patch conv (layers 1..3) -----------------------------
// Block = one (b,p), 256 threads = 4 waves; wave w owns pixel ntile w.
// im2col LDS [n][k] fp16 hi/lo, row stride STRIDE halves (bank-safe).
template<int CIN, int COUT, int KS, int STRIDE>
__global__ __launch_bounds__(256) void pce_mfma(
    const float* __restrict__ Xin,   // [B][256][CIN][64]
    const unsigned short* __restrict__ wA,
    const float* __restrict__ eb,    // [NE*COUT]
    const float* __restrict__ probs, // [256][8]
    float* __restrict__ Xout)        // [B][256][COUT][64]
{
    constexpr int MT  = (NE * COUT) / 16;
    constexpr int MPE = COUT / 16;        // mtiles per expert (1 or 2)
    int bx = blockIdx.x;
    int b = bx >> 8, p = bx & 255;
    int tid = threadIdx.x;

    __shared__ float sp[CIN][10][12];
    __shared__ unsigned int imh[(64 * STRIDE) / 2];
    __shared__ unsigned int iml[(64 * STRIDE) / 2];
    __shared__ float se[8];
    __shared__ float sb[NE * COUT];
    __shared__ int mlist[MT];
    __shared__ int mcount;

    for (int t = tid; t < CIN * 120; t += 256) ((float*)sp)[t] = 0.0f;
    if (tid < 8) se[tid] = probs[p * 8 + tid];
    if (tid < NE * COUT) sb[tid] = eb[tid];
    __syncthreads();

    if (tid == 0) {
        int n = 0;
        for (int e = 0; e < 8; ++e)
            if (se[e] > 0.0f)
                for (int u = 0; u < MPE; ++u) mlist[n++] = e * MPE + u;
        mcount = n;
    }
    for (int t = tid; t < CIN * 64; t += 256) {
        int cin = t >> 6, pix = t & 63, i = pix >> 3, j = pix & 7;
        sp[cin][i + 1][j + 1] = Xin[((size_t)(b * 256 + p) * CIN + cin) * 64 + pix];
    }
    __syncthreads();

    // Build im2col hi/lo planes: task = (n, cin) -> 12 halves at [n][cin*12].
    for (int task = tid; task < 64 * CIN; task += 256) {
        int n = task & 63, cin = task >> 6;
        int pr = n >> 3, pc = n & 7;
        float v[12];
        #pragma unroll
        for (int dy = 0; dy < 3; ++dy)
            #pragma unroll
            for (int dx = 0; dx < 3; ++dx)
                v[dy * 3 + dx] = sp[cin][pr + dy][pc + dx];
        v[9] = v[10] = v[11] = 0.0f;
        int ub = (n * STRIDE + cin * 12) >> 1;   // uint index
        #pragma unroll
        for (int t2 = 0; t2 < 6; ++t2) {
            float x0 = v[2*t2], x1 = v[2*t2+1];
            _Float16 h0 = (_Float16)x0, h1 = (_Float16)x1;
            _Float16 l0 = (_Float16)(x0 - (float)h0);
            _Float16 l1 = (_Float16)(x1 - (float)h1);
            imh[ub + t2] = pack2(h0, h1);
            iml[ub + t2] = pack2(l0, l1);
        }
    }
    __syncthreads();

    int nt = tid >> 6, l = tid & 63;
    int row4 = (l >> 4) * 4;

    // B fragments for this wave's ntile (held across all mtiles)
    half8 Bh[KS], Bl[KS];
    int boff = (nt * 16 + (l & 15)) * STRIDE + (l >> 4) * 8;
    #pragma unroll
    for (int ks = 0; ks < KS; ++ks) {
        Bh[ks] = *(const half8*)((const unsigned short*)imh + boff + ks * 32);
        Bl[ks] = *(const half8*)((const unsigned short*)iml + boff + ks * 32);
    }

    f32x4 acc0 = {0.f, 0.f, 0.f, 0.f};
    f32x4 acc1 = {0.f, 0.f, 0.f, 0.f};

    int mc = mcount;
    for (int mi = 0; mi < mc; ++mi) {
        int mt = mlist[mi];
        const unsigned short* ap = wA + (size_t)mt * KS * 512 + l * 8;
        f32x4 ctmp = {0.f, 0.f, 0.f, 0.f};
        #pragma unroll
        for (int ks = 0; ks < KS; ++ks) {
            half8 a = *(const half8*)(ap + ks * 512);
            ctmp = __builtin_amdgcn_mfma_f32_16x16x32_f16(a, Bh[ks], ctmp, 0, 0, 0);
            ctmp = __builtin_amdgcn_mfma_f32_16x16x32_f16(a, Bl[ks], ctmp, 0, 0, 0);
        }
        float pe = se[mt / MPE];
        #pragma unroll
        for (int j = 0; j < 4; ++j) {
            int m = mt * 16 + row4 + j;
            float r = fmaxf(ctmp[j] + sb[m], 0.0f) * pe;
            if (MPE == 2) { if (mt & 1) acc1[j] += r; else acc0[j] += r; }
            else acc0[j] += r;
        }
    }

    int n = nt * 16 + (l & 15);
    float* op = Xout + (size_t)(b * 256 + p) * COUT * 64 + n;
    #pragma unroll
    for (int j = 0; j < 4; ++j) op[(size_t)(row4 + j) * 64] = acc0[j];
    if (MPE == 2) {
        #pragma unroll
        for (int j = 0; j < 4; ++j) op[(size_t)(16 + row4 + j) * 64] = acc1[j];
    }
}

// ---------------- fp32 path for layer 0 (tiny: CIN=3, COUT=8) ---------------
template<int CIN, int COUT, int PPT, int KC>
__device__ __forceinline__ void conv_chunk(
    const float (*sp)[10][12], const float* __restrict__ ew,
    const float* __restrict__ eb,
    const int* e_ids, const float* e_ps,
    int cout, int row, int col0, float* fin)
{
    float acc[KC][PPT];
    #pragma unroll
    for (int u = 0; u < KC; ++u)
        #pragma unroll
        for (int q = 0; q < PPT; ++q) acc[u][q] = 0.0f;

    const float* wb[KC];
    #pragma unroll
    for (int u = 0; u < KC; ++u)
        wb[u] = ew + (size_t)(e_ids[u] * COUT + cout) * CIN * 9;

    for (int cin = 0; cin < CIN; ++cin) {
        float win[3][PPT + 2];
        #pragma unroll
        for (int r = 0; r < 3; ++r)
            #pragma unroll
            for (int cc = 0; cc < PPT + 2; ++cc)
                win[r][cc] = sp[cin][row + r][col0 + cc];

        #pragma unroll
        for (int u = 0; u < KC; ++u) {
            const float* wp = wb[u] + cin * 9;
            #pragma unroll
            for (int r = 0; r < 3; ++r) {
                float w0 = wp[r*3+0], w1 = wp[r*3+1], w2 = wp[r*3+2];
                #pragma unroll
                for (int q = 0; q < PPT; ++q)
                    acc[u][q] = fmaf(w0, win[r][q],
                                fmaf(w1, win[r][q+1],
                                fmaf(w2, win[r][q+2], acc[u][q])));
            }
        }
    }
    #pragma unroll
    for (int u = 0; u < KC; ++u) {
        float bias = eb[e_ids[u] * COUT + cout];
        float pe = e_ps[u];
        #pragma unroll
        for (int q = 0; q < PPT; ++q)
            fin[q] += pe * fmaxf(acc[u][q] + bias, 0.0f);
    }
}

template<int CIN, int COUT, bool NCHW_IN>
__global__ __launch_bounds__(256) void pce_conv(
    const float* __restrict__ Xin,
    const float* __restrict__ ew,
    const float* __restrict__ eb,
    const float* __restrict__ probs,
    float* __restrict__ Xout)
{
    constexpr int PPT = (COUT * 64) / 256;
    constexpr int TPC = 64 / PPT;
    int bx = blockIdx.x;
    int b = bx >> 8, p = bx & 255;
    int py = p >> 4, px = p & 15;
    int tid = threadIdx.x;

    __shared__ float sp[CIN][10][12];
    __shared__ float se[8];
    __shared__ int   sk[8];
    __shared__ int   skn;

    for (int t = tid; t < CIN * 120; t += 256) ((float*)sp)[t] = 0.0f;
    if (tid < 8) se[tid] = probs[p * 8 + tid];
    __syncthreads();

    if (tid == 0) {
        int n = 0;
        for (int e = 0; e < 8; ++e) if (se[e] > 0.0f) { sk[n] = e; ++n; }
        skn = n;
    }
    for (int t = tid; t < CIN * 64; t += 256) {
        int cin = t >> 6, pix = t & 63, i = pix >> 3, j = pix & 7;
        float v;
        if (NCHW_IN)
            v = Xin[((b * CIN + cin) * 128 + (py * 8 + i)) * 128 + (px * 8 + j)];
        else
            v = Xin[((size_t)(b * 256 + p) * CIN + cin) * 64 + pix];
        sp[cin][i + 1][j + 1] = v;
    }
    __syncthreads();

    int cout = tid / TPC, sub = tid % TPC;
    int pix0 = sub * PPT;
    int row = pix0 >> 3, col0 = pix0 & 7;
    int k = skn;

    float fin[PPT];
    #pragma unroll
    for (int q = 0; q < PPT; ++q) fin[q] = 0.0f;

    int ei = 0;
    for (; ei + 1 < k; ei += 2) {
        int   eid[2] = { sk[ei], sk[ei + 1] };
        float eps[2] = { se[eid[0]], se[eid[1]] };
        conv_chunk<CIN, COUT, PPT, 2>(sp, ew, eb, eid, eps, cout, row, col0, fin);
    }
    if (ei < k) {
        int   eid[1] = { sk[ei] };
        float eps[1] = { se[eid[0]] };
        conv_chunk<CIN, COUT, PPT, 1>(sp, ew, eb, eid, eps, cout, row, col0, fin);
    }

    float* op = Xout + ((size_t)(b * 256 + p) * COUT + cout) * 64 + pix0;
    #pragma unroll
    for (int q = 0; q < PPT; ++q) op[q] = fin[q];
}

// ---------------- Fused 16x16 mean-pool + FC --------------------------------
__global__ __launch_bounds__(256) void pool_fc(
    const float* __restrict__ Xp,
    const float* __restrict__ fcw,
    const float* __restrict__ fcb,
    float* __restrict__ out)
{
    int b = blockIdx.x;
    __shared__ float pooled[2048];
    for (int idx = threadIdx.x; idx < 2048; idx += 256) {
        int cch = idx >> 6, oy = (idx >> 3) & 7, ox = idx & 7;
        float s = 0.0f;
        #pragma unroll
        for (int dy = 0; dy < 2; ++dy)
            #pragma unroll
            for (int dx = 0; dx < 2; ++dx) {
                int p = (2 * oy + dy) * 16 + (2 * ox + dx);
                const float* q = Xp + ((size_t)(b * 256 + p) * 32 + cch) * 64;
                for (int kk = 0; kk < 64; ++kk) s += q[kk];
            }
        pooled[idx] = s * (1.0f / 256.0f);
    }
    __syncthreads();

    int wave = threadIdx.x >> 6, lane = threadIdx.x & 63;
    for (int cls = wave; cls < 100; cls += 4) {
        float a = 0.0f;
        #pragma unroll
        for (int r = 0; r < 32; ++r)
            a += pooled[r * 64 + lane] * fcw[(size_t)cls * 2048 + r * 64 + lane];
        #pragma unroll
        for (int off = 32; off > 0; off >>= 1) a += __shfl_down(a, off);
        if (lane == 0) out[b * 100 + cls] = a + fcb[cls];
    }
}

// ---------------- Launch ----------------------------------------------------
extern "C" void kernel_launch(void* const* d_in, const int* in_sizes, int n_in,
                              void* d_out, int out_size, void* d_ws, size_t ws_size,
                              hipStream_t stream) {
    const float* X = (const float*)d_in[0];
    const float* ew[4]; const float* eb[4];
    const float* rw[4]; const float* rb[4];
    const float* rlw[4]; const float* rlb[4];
    for (int l = 0; l < 4; ++l) {
        ew[l]  = (const float*)d_in[1 + 6*l + 0];
        eb[l]  = (const float*)d_in[1 + 6*l + 1];
        rw[l]  = (const float*)d_in[1 + 6*l + 2];
        rb[l]  = (const float*)d_in[1 + 6*l + 3];
        rlw[l] = (const float*)d_in[1 + 6*l + 4];
        rlb[l] = (const float*)d_in[1 + 6*l + 5];
    }
    const float* fcw = (const float*)d_in[25];
    const float* fcb = (const float*)d_in[26];

    float* probs = (float*)d_ws;                       // 32 KB
    float* buf0 = (float*)((char*)d_ws + 32768);       // 16.78 MB max
    float* buf1 = buf0 + (size_t)16 * 256 * 16 * 64;   // 33.55 MB max
    // prepped fp16 weight fragments after buf1
    unsigned short* wA1 = (unsigned short*)(buf1 + (size_t)16 * 256 * 32 * 64);
    unsigned short* wA2 = wA1 + 8 * 3 * 512;           // L1: MT=8, KS=3
    unsigned short* wA3 = wA2 + 8 * 6 * 512;           // L2: MT=8, KS=6
    // L3: MT=16, KS=6 -> 49152 halves

    for (int l = 0; l < 4; ++l)
        router_kernel<<<256, 64, 0, stream>>>(rw[l], rb[l], rlw[l], rlb[l],
                                              probs + l * 256 * 8);

    prep_w<8, 16, 3><<<(8*3*512 + 255)/256, 256, 0, stream>>>(ew[1], wA1);
    prep_w<16, 16, 6><<<(8*6*512 + 255)/256, 256, 0, stream>>>(ew[2], wA2);
    prep_w<16, 32, 6><<<(16*6*512 + 255)/256, 256, 0, stream>>>(ew[3], wA3);

    pce_conv<3, 8, true><<<4096, 256, 0, stream>>>(X, ew[0], eb[0], probs + 0*2048, buf0);

    pce_mfma<8, 16, 3, 104><<<4096, 256, 0, stream>>>(buf0, wA1, eb[1], probs + 1*2048, buf1);
    pce_mfma<16, 16, 6, 200><<<4096, 256, 0, stream>>>(buf1, wA2, eb[2], probs + 2*2048, buf0);
    pce_mfma<16, 32, 6, 200><<<4096, 256, 0, stream>>>(buf0, wA3, eb[3], probs + 3*2048, buf1);

    pool_fc<<<16, 256, 0, stream>>>(buf1, fcw, fcb, (float*)d_out);
}

// Round 4
// 185.399 us; speedup vs baseline: 6.9877x; 2.1401x over previous
//
#include <hip/hip_runtime.h>
#include <math.h>

#define NE 8
#define PI_F 3.14159265358979323846f

typedef _Float16 half8 __attribute__((ext_vector_type(8)));
typedef float f32x4 __attribute__((ext_vector_type(4)));

// ---------------- Routers for all 4 layers in one launch --------------------
struct RouterArgs {
    const float* rw[4]; const float* rb[4];
    const float* rlw[4]; const float* rlb[4];
};

__global__ __launch_bounds__(64) void router_all(RouterArgs ra, float* __restrict__ probs)
{
    int layer = blockIdx.y;
    const float* rw = ra.rw[layer];  const float* rb = ra.rb[layer];
    const float* rlw = ra.rlw[layer]; const float* rlb = ra.rlb[layer];
    float* pout = probs + layer * 2048;

    int p = blockIdx.x;
    int lane = threadIdx.x;
    int py = p >> 4, px = p & 15;
    int i = lane >> 3, j = lane & 7;
    int y = py * 8 + i, x = px * 8 + j;

    float base0 = (x + 0.5f) / 128.0f;
    float base1 = (y + 0.5f) / 128.0f;
    float base2 = (j + 0.5f) / 8.0f;
    float base3 = (i + 0.5f) / 8.0f;

    float coord[52];
    coord[0] = base0; coord[1] = base1; coord[2] = base2; coord[3] = base3;
    int c = 4;
    #pragma unroll
    for (int f = 0; f < 6; ++f) {
        float w = PI_F * (float)(1 << f);
        coord[c+0] = sinf(w * base0); coord[c+1] = sinf(w * base1);
        coord[c+2] = sinf(w * base2); coord[c+3] = sinf(w * base3);
        coord[c+4] = cosf(w * base0); coord[c+5] = cosf(w * base1);
        coord[c+6] = cosf(w * base2); coord[c+7] = cosf(w * base3);
        c += 8;
    }

    float z[16];
    #pragma unroll
    for (int r = 0; r < 16; ++r) {
        float a = rb[r];
        #pragma unroll
        for (int cc = 0; cc < 52; ++cc) a += rw[r*52 + cc] * coord[cc];
        z[r] = fmaxf(a, 0.0f);
    }
    #pragma unroll
    for (int r = 0; r < 16; ++r) {
        float v = z[r];
        #pragma unroll
        for (int off = 32; off > 0; off >>= 1) v += __shfl_xor(v, off);
        z[r] = v * (1.0f / 64.0f);
    }

    int e = lane & 7;
    float logit = rlb[e];
    #pragma unroll
    for (int r = 0; r < 16; ++r) logit += rlw[e*16 + r] * z[r];

    float m = logit;
    #pragma unroll
    for (int off = 4; off > 0; off >>= 1) m = fmaxf(m, __shfl_xor(m, off));
    float ex = expf(logit - m);
    float s = ex;
    #pragma unroll
    for (int off = 4; off > 0; off >>= 1) s += __shfl_xor(s, off);
    float pr = ex / s;
    pr = (pr >= 0.05f) ? pr : 0.0f;
    float s2 = pr;
    #pragma unroll
    for (int off = 4; off > 0; off >>= 1) s2 += __shfl_xor(s2, off);
    pr = pr / (s2 + 1e-9f);
    if (lane < 8) pout[p*8 + lane] = pr;
}

// ---------------- Weight prep: fp16 A-fragments, lane-swizzled --------------
// k-map: k = r*CSTR + cin (r = k/CSTR, cin = k%CSTR). m padded to COUT_P.
template<int CIN, int COUT_R, int COUT_P, int CSTR, int KS>
__global__ __launch_bounds__(256) void prep_w(
    const float* __restrict__ ew, unsigned short* __restrict__ wA)
{
    constexpr int MT = (NE * COUT_P) / 16;
    int idx = blockIdx.x * 256 + threadIdx.x;
    int total = MT * KS * 512;
    if (idx >= total) return;
    int j    = idx & 7;
    int lane = (idx >> 3) & 63;
    int t2   = idx >> 9;
    int ks   = t2 % KS;
    int mt   = t2 / KS;
    int m    = mt * 16 + (lane & 15);
    int e    = m / COUT_P, row = m % COUT_P;
    int k    = ks * 32 + (lane >> 4) * 8 + j;
    int cin  = k % CSTR, r = k / CSTR;
    float val = 0.0f;
    if (row < COUT_R && cin < CIN && r < 9)
        val = ew[((size_t)(e * COUT_R + row) * CIN + cin) * 9 + r];
    union { _Float16 h1; unsigned short u; } cv;
    cv.h1 = (_Float16)val;
    wA[idx] = cv.u;
}

// ---------------- MFMA patch conv, register im2col + A-prefetch -------------
// Block = one (b,p), 4 waves; wave nt owns pixels nt*16..nt*16+15.
template<int CIN, int COUT_R, int COUT_P, int CSTR, int KS, bool NCHW_IN>
__global__ __launch_bounds__(256, 3) void pce_mfma(
    const float* __restrict__ Xin,
    const unsigned short* __restrict__ wA,
    const float* __restrict__ eb,     // [NE*COUT_R]
    const float* __restrict__ probs,  // [256][8]
    float* __restrict__ Xout)         // [B][256][COUT_R][64]
{
    constexpr int MT  = (NE * COUT_P) / 16;
    constexpr int MPE = COUT_P / 16;
    int bx = blockIdx.x;
    int b = bx >> 8, p = bx & 255;
    int py = p >> 4, px = p & 15;
    int tid = threadIdx.x;

    __shared__ float sp[CIN][10][12];
    __shared__ float se[8];
    __shared__ float sb[MT * 16];
    __shared__ int   mlist[MT];
    __shared__ int   mcount;

    // halo zero-fill: 40 cells per cin (row0, row9, rows1-8 x cols {0,9})
    for (int t = tid; t < CIN * 40; t += 256) {
        int cin = t / 40, h = t % 40;
        int r, c;
        if (h < 12)       { r = 0; c = h; }
        else if (h < 24)  { r = 9; c = h - 12; }
        else              { r = 1 + (h - 24) / 2; c = ((h - 24) & 1) ? 9 : 0; }
        sp[cin][r][c] = 0.0f;
    }
    // interior stage (disjoint from halo)
    for (int t = tid; t < CIN * 64; t += 256) {
        int cin = t >> 6, pix = t & 63, i = pix >> 3, j = pix & 7;
        float v;
        if (NCHW_IN)
            v = Xin[((size_t)(b * CIN + cin) * 128 + (py * 8 + i)) * 128 + (px * 8 + j)];
        else
            v = Xin[((size_t)(b * 256 + p) * CIN + cin) * 64 + pix];
        sp[cin][i + 1][j + 1] = v;
    }
    if (tid < 8) se[tid] = probs[p * 8 + tid];
    if (tid < MT * 16) {
        int e = tid / COUT_P, row = tid % COUT_P;
        sb[tid] = (row < COUT_R) ? eb[e * COUT_R + row] : 0.0f;
    }
    if (tid == 0) {
        int n = 0;
        for (int e = 0; e < 8; ++e) {
            float pe = probs[p * 8 + e];
            if (pe > 0.0f)
                for (int u = 0; u < MPE; ++u) mlist[n++] = e * MPE + u;
        }
        mcount = n;
    }
    __syncthreads();

    int l = tid & 63, nt = tid >> 6;
    int n = nt * 16 + (l & 15);
    int pr = (l & 15) >> 3 | (nt << 1);      // n>>3
    int pc = l & 7;                          // n&7  (n = nt*16 + (l&15))
    // recompute cleanly:
    pr = n >> 3; pc = n & 7;
    int lane4 = l >> 4;
    int row4 = lane4 * 4;

    // Build hi/lo B-fragments in registers directly from sp
    half8 Bh[KS], Bl[KS];
    #pragma unroll
    for (int ks = 0; ks < KS; ++ks) {
        #pragma unroll
        for (int j = 0; j < 8; ++j) {
            int k = ks * 32 + lane4 * 8 + j;
            int cin = k % CSTR, r = k / CSTR;
            float v = 0.0f;
            if (r < 9 && cin < CIN)
                v = sp[cin][pr + r / 3][pc + r % 3];
            _Float16 h = (_Float16)v;
            Bh[ks][j] = h;
            Bl[ks][j] = (_Float16)(v - (float)h);
        }
    }

    f32x4 acc0 = {0.f, 0.f, 0.f, 0.f};
    f32x4 acc1 = {0.f, 0.f, 0.f, 0.f};

    int mc = mcount;
    const unsigned short* apbase = wA + l * 8;
    half8 Acur[KS], Anxt[KS];
    int mt0 = mlist[0];
    #pragma unroll
    for (int ks = 0; ks < KS; ++ks)
        Acur[ks] = *(const half8*)(apbase + ((size_t)mt0 * KS + ks) * 512);

    for (int mi = 0; mi < mc; ++mi) {
        int mt = mlist[mi];
        int mtn = (mi + 1 < mc) ? mlist[mi + 1] : mt0;
        #pragma unroll
        for (int ks = 0; ks < KS; ++ks)
            Anxt[ks] = *(const half8*)(apbase + ((size_t)mtn * KS + ks) * 512);

        f32x4 ct = {0.f, 0.f, 0.f, 0.f};
        #pragma unroll
        for (int ks = 0; ks < KS; ++ks) {
            ct = __builtin_amdgcn_mfma_f32_16x16x32_f16(Acur[ks], Bh[ks], ct, 0, 0, 0);
            ct = __builtin_amdgcn_mfma_f32_16x16x32_f16(Acur[ks], Bl[ks], ct, 0, 0, 0);
        }

        float pe = se[mt / MPE];
        #pragma unroll
        for (int j = 0; j < 4; ++j) {
            float r = fmaxf(ct[j] + sb[mt * 16 + row4 + j], 0.0f) * pe;
            if (MPE == 2) { if (mt & 1) acc1[j] += r; else acc0[j] += r; }
            else acc0[j] += r;
        }
        #pragma unroll
        for (int ks = 0; ks < KS; ++ks) Acur[ks] = Anxt[ks];
    }

    float* op = Xout + (size_t)(b * 256 + p) * COUT_R * 64 + n;
    if (COUT_R < COUT_P) {           // L0: only rows < COUT_R valid
        if (row4 < COUT_R) {
            #pragma unroll
            for (int j = 0; j < 4; ++j) op[(size_t)(row4 + j) * 64] = acc0[j];
        }
    } else {
        #pragma unroll
        for (int j = 0; j < 4; ++j) op[(size_t)(row4 + j) * 64] = acc0[j];
        if (MPE == 2) {
            #pragma unroll
            for (int j = 0; j < 4; ++j) op[(size_t)(16 + row4 + j) * 64] = acc1[j];
        }
    }
}

// ---------------- Pool: [16][256][32][64] -> pooled [16][2048] --------------
__global__ __launch_bounds__(256) void pool_kernel(
    const float* __restrict__ Xp, float* __restrict__ pooled)
{
    int idx = blockIdx.x * 256 + threadIdx.x;
    if (idx >= 16 * 2048) return;
    int b = idx >> 11, r = idx & 2047;
    int c = r >> 6, oy = (r >> 3) & 7, ox = r & 7;
    float s = 0.0f;
    #pragma unroll
    for (int dy = 0; dy < 2; ++dy)
        #pragma unroll
        for (int dx = 0; dx < 2; ++dx) {
            int p = (2 * oy + dy) * 16 + (2 * ox + dx);
            const f32x4* q = (const f32x4*)(Xp + ((size_t)(b * 256 + p) * 32 + c) * 64);
            #pragma unroll
            for (int kk = 0; kk < 16; ++kk) {
                f32x4 v = q[kk];
                s += v.x + v.y + v.z + v.w;
            }
        }
    pooled[idx] = s * (1.0f / 256.0f);
}

// ---------------- FC: pooled [16][2048] x fcw [100][2048] -------------------
__global__ __launch_bounds__(256) void fc_kernel(
    const float* __restrict__ pooled, const float* __restrict__ fcw,
    const float* __restrict__ fcb, float* __restrict__ out)
{
    int b = blockIdx.x;
    __shared__ float spb[2048];
    for (int t = threadIdx.x; t < 2048; t += 256) spb[t] = pooled[b * 2048 + t];
    __syncthreads();

    int wave = threadIdx.x >> 6, lane = threadIdx.x & 63;
    for (int cls = wave; cls < 100; cls += 4) {
        float a = 0.0f;
        #pragma unroll
        for (int r = 0; r < 32; ++r)
            a += spb[r * 64 + lane] * fcw[(size_t)cls * 2048 + r * 64 + lane];
        #pragma unroll
        for (int off = 32; off > 0; off >>= 1) a += __shfl_down(a, off);
        if (lane == 0) out[b * 100 + cls] = a + fcb[cls];
    }
}

// ---------------- Launch ----------------------------------------------------
extern "C" void kernel_launch(void* const* d_in, const int* in_sizes, int n_in,
                              void* d_out, int out_size, void* d_ws, size_t ws_size,
                              hipStream_t stream) {
    const float* X = (const float*)d_in[0];
    const float* ew[4]; const float* eb[4];
    RouterArgs ra;
    for (int l = 0; l < 4; ++l) {
        ew[l]    = (const float*)d_in[1 + 6*l + 0];
        eb[l]    = (const float*)d_in[1 + 6*l + 1];
        ra.rw[l]  = (const float*)d_in[1 + 6*l + 2];
        ra.rb[l]  = (const float*)d_in[1 + 6*l + 3];
        ra.rlw[l] = (const float*)d_in[1 + 6*l + 4];
        ra.rlb[l] = (const float*)d_in[1 + 6*l + 5];
    }
    const float* fcw = (const float*)d_in[25];
    const float* fcb = (const float*)d_in[26];

    char* ws = (char*)d_ws;
    float* probs  = (float*)ws;                      // 4*2048 f = 32 KB
    float* pooled = (float*)(ws + 32768);            // 32768 f = 128 KB
    unsigned short* wA0 = (unsigned short*)(ws + 32768 + 131072);       // 8*1*512
    unsigned short* wA1 = wA0 + 8 * 1 * 512;                            // 8*3*512
    unsigned short* wA2 = wA1 + 8 * 3 * 512;                            // 8*5*512
    unsigned short* wA3 = wA2 + 8 * 5 * 512;                            // 16*5*512
    float* buf0 = (float*)(ws + 524288);             // 16 MB max
    float* buf1 = buf0 + (size_t)16 * 256 * 16 * 64; // 32 MB max

    router_all<<<dim3(256, 4), 64, 0, stream>>>(ra, probs);

    prep_w<3, 8, 16, 3, 1><<<(8*1*512 + 255)/256, 256, 0, stream>>>(ew[0], wA0);
    prep_w<8, 16, 16, 8, 3><<<(8*3*512 + 255)/256, 256, 0, stream>>>(ew[1], wA1);
    prep_w<16, 16, 16, 16, 5><<<(8*5*512 + 255)/256, 256, 0, stream>>>(ew[2], wA2);
    prep_w<16, 32, 32, 16, 5><<<(16*5*512 + 255)/256, 256, 0, stream>>>(ew[3], wA3);

    pce_mfma<3, 8, 16, 3, 1, true  ><<<4096, 256, 0, stream>>>(X,    wA0, eb[0], probs + 0*2048, buf0);
    pce_mfma<8, 16, 16, 8, 3, false><<<4096, 256, 0, stream>>>(buf0, wA1, eb[1], probs + 1*2048, buf1);
    pce_mfma<16, 16, 16, 16, 5, false><<<4096, 256, 0, stream>>>(buf1, wA2, eb[2], probs + 2*2048, buf0);
    pce_mfma<16, 32, 32, 16, 5, false><<<4096, 256, 0, stream>>>(buf0, wA3, eb[3], probs + 3*2048, buf1);

    pool_kernel<<<128, 256, 0, stream>>>(buf1, pooled);
    fc_kernel<<<16, 256, 0, stream>>>(pooled, fcw, fcb, (float*)d_out);
}

// Round 5
// 138.387 us; speedup vs baseline: 9.3616x; 1.3397x over previous
//
#include <hip/hip_runtime.h>
#include <math.h>

#define NE 8
#define PI_F 3.14159265358979323846f

typedef _Float16 half8 __attribute__((ext_vector_type(8)));
typedef float f32x4 __attribute__((ext_vector_type(4)));

// ---------------- Routers for all 4 layers in one launch --------------------
struct RouterArgs {
    const float* rw[4]; const float* rb[4];
    const float* rlw[4]; const float* rlb[4];
};

__global__ __launch_bounds__(64) void router_all(RouterArgs ra, float* __restrict__ probs)
{
    int layer = blockIdx.y;
    const float* rw = ra.rw[layer];  const float* rb = ra.rb[layer];
    const float* rlw = ra.rlw[layer]; const float* rlb = ra.rlb[layer];
    float* pout = probs + layer * 2048;

    int p = blockIdx.x;
    int lane = threadIdx.x;
    int py = p >> 4, px = p & 15;
    int i = lane >> 3, j = lane & 7;
    int y = py * 8 + i, x = px * 8 + j;

    float base0 = (x + 0.5f) / 128.0f;
    float base1 = (y + 0.5f) / 128.0f;
    float base2 = (j + 0.5f) / 8.0f;
    float base3 = (i + 0.5f) / 8.0f;

    float coord[52];
    coord[0] = base0; coord[1] = base1; coord[2] = base2; coord[3] = base3;
    int c = 4;
    #pragma unroll
    for (int f = 0; f < 6; ++f) {
        float w = PI_F * (float)(1 << f);
        coord[c+0] = sinf(w * base0); coord[c+1] = sinf(w * base1);
        coord[c+2] = sinf(w * base2); coord[c+3] = sinf(w * base3);
        coord[c+4] = cosf(w * base0); coord[c+5] = cosf(w * base1);
        coord[c+6] = cosf(w * base2); coord[c+7] = cosf(w * base3);
        c += 8;
    }

    float z[16];
    #pragma unroll
    for (int r = 0; r < 16; ++r) {
        float a = rb[r];
        #pragma unroll
        for (int cc = 0; cc < 52; ++cc) a += rw[r*52 + cc] * coord[cc];
        z[r] = fmaxf(a, 0.0f);
    }
    #pragma unroll
    for (int r = 0; r < 16; ++r) {
        float v = z[r];
        #pragma unroll
        for (int off = 32; off > 0; off >>= 1) v += __shfl_xor(v, off);
        z[r] = v * (1.0f / 64.0f);
    }

    int e = lane & 7;
    float logit = rlb[e];
    #pragma unroll
    for (int r = 0; r < 16; ++r) logit += rlw[e*16 + r] * z[r];

    float m = logit;
    #pragma unroll
    for (int off = 4; off > 0; off >>= 1) m = fmaxf(m, __shfl_xor(m, off));
    float ex = expf(logit - m);
    float s = ex;
    #pragma unroll
    for (int off = 4; off > 0; off >>= 1) s += __shfl_xor(s, off);
    float pr = ex / s;
    pr = (pr >= 0.05f) ? pr : 0.0f;
    float s2 = pr;
    #pragma unroll
    for (int off = 4; off > 0; off >>= 1) s2 += __shfl_xor(s2, off);
    pr = pr / (s2 + 1e-9f);
    if (lane < 8) pout[p*8 + lane] = pr;
}

// ---------------- Weight prep: fp16 A-fragments, all layers, one launch -----
template<int CIN, int COUT_R, int COUT_P, int CSTR, int KS>
__device__ __forceinline__ void prep_one(
    const float* __restrict__ ew, unsigned short* __restrict__ wA, int idx)
{
    int j    = idx & 7;
    int lane = (idx >> 3) & 63;
    int t2   = idx >> 9;
    int ks   = t2 % KS;
    int mt   = t2 / KS;
    int m    = mt * 16 + (lane & 15);
    int e    = m / COUT_P, row = m % COUT_P;
    int k    = ks * 32 + (lane >> 4) * 8 + j;
    int cin  = k % CSTR, r = k / CSTR;
    float val = 0.0f;
    if (row < COUT_R && cin < CIN && r < 9)
        val = ew[((size_t)(e * COUT_R + row) * CIN + cin) * 9 + r];
    union { _Float16 h1; unsigned short u; } cv;
    cv.h1 = (_Float16)val;
    wA[idx] = cv.u;
}

__global__ __launch_bounds__(256) void prep_all(
    const float* __restrict__ ew0, const float* __restrict__ ew1,
    const float* __restrict__ ew2, const float* __restrict__ ew3,
    unsigned short* __restrict__ wA0, unsigned short* __restrict__ wA1,
    unsigned short* __restrict__ wA2, unsigned short* __restrict__ wA3)
{
    int idx = blockIdx.x * 256 + threadIdx.x;
    if (idx < 4096)        prep_one<3, 8, 16, 3, 1>(ew0, wA0, idx);
    else if (idx < 16384)  prep_one<8, 16, 16, 8, 3>(ew1, wA1, idx - 4096);
    else if (idx < 36864)  prep_one<16, 16, 16, 16, 5>(ew2, wA2, idx - 16384);
    else if (idx < 77824)  prep_one<16, 32, 32, 16, 5>(ew3, wA3, idx - 36864);
}

// ---------------- One layer inside the fused kernel -------------------------
template<int CIN, int COUT_R, int COUT_P, int CSTR, int KS, bool FLAT_OUT>
__device__ __forceinline__ void layer_run(
    const float (*spin)[10][13], float* spout,
    const unsigned short* __restrict__ wA,
    const float* sbL, const float* seL, const int* mlL, int mc,
    int l, int lane4, int pr, int pc, int row4, int n)
{
    constexpr int MPE = COUT_P / 16;

    // Build hi/lo B-fragments in registers from LDS halo patch
    half8 Bh[KS], Bl[KS];
    #pragma unroll
    for (int ks = 0; ks < KS; ++ks) {
        #pragma unroll
        for (int j = 0; j < 8; ++j) {
            int k = ks * 32 + lane4 * 8 + j;
            int cin = k % CSTR, r = k / CSTR;
            float v = 0.0f;
            if (r < 9 && cin < CIN)
                v = spin[cin][pr + r / 3][pc + r % 3];
            _Float16 h = (_Float16)v;
            Bh[ks][j] = h;
            Bl[ks][j] = (_Float16)(v - (float)h);
        }
    }

    f32x4 acc0 = {0.f, 0.f, 0.f, 0.f};
    f32x4 acc1 = {0.f, 0.f, 0.f, 0.f};

    const unsigned short* apbase = wA + l * 8;
    half8 Acur[KS], Anxt[KS];
    int mt0 = mlL[0];
    #pragma unroll
    for (int ks = 0; ks < KS; ++ks)
        Acur[ks] = *(const half8*)(apbase + ((size_t)mt0 * KS + ks) * 512);

    for (int mi = 0; mi < mc; ++mi) {
        int mt = mlL[mi];
        int mtn = (mi + 1 < mc) ? mlL[mi + 1] : mt0;
        #pragma unroll
        for (int ks = 0; ks < KS; ++ks)
            Anxt[ks] = *(const half8*)(apbase + ((size_t)mtn * KS + ks) * 512);

        // independent hi/lo accumulation chains (2x MFMA ILP)
        f32x4 cth = {0.f, 0.f, 0.f, 0.f};
        f32x4 ctl = {0.f, 0.f, 0.f, 0.f};
        #pragma unroll
        for (int ks = 0; ks < KS; ++ks) {
            cth = __builtin_amdgcn_mfma_f32_16x16x32_f16(Acur[ks], Bh[ks], cth, 0, 0, 0);
            ctl = __builtin_amdgcn_mfma_f32_16x16x32_f16(Acur[ks], Bl[ks], ctl, 0, 0, 0);
        }

        float pe = seL[(MPE == 2) ? (mt >> 1) : mt];
        #pragma unroll
        for (int j = 0; j < 4; ++j) {
            float rr = fmaxf(cth[j] + ctl[j] + sbL[mt * 16 + row4 + j], 0.0f) * pe;
            if (MPE == 2) { if (mt & 1) acc1[j] += rr; else acc0[j] += rr; }
            else acc0[j] += rr;
        }
        #pragma unroll
        for (int ks = 0; ks < KS; ++ks) Acur[ks] = Anxt[ks];
    }

    if (FLAT_OUT) {
        #pragma unroll
        for (int j = 0; j < 4; ++j) spout[(row4 + j) * 64 + n] = acc0[j];
        if (MPE == 2) {
            #pragma unroll
            for (int j = 0; j < 4; ++j) spout[(16 + row4 + j) * 64 + n] = acc1[j];
        }
    } else {
        float (*so)[10][13] = (float (*)[10][13])spout;
        if (COUT_R == COUT_P || row4 < COUT_R) {
            #pragma unroll
            for (int j = 0; j < 4; ++j) so[row4 + j][1 + pr][1 + pc] = acc0[j];
        }
    }
}

// ---------------- Fused all-4-layer conv + per-patch channel sums -----------
__global__ __launch_bounds__(256) void pce_fused(
    const float* __restrict__ X,
    const unsigned short* __restrict__ wA0, const unsigned short* __restrict__ wA1,
    const unsigned short* __restrict__ wA2, const unsigned short* __restrict__ wA3,
    const float* __restrict__ eb0, const float* __restrict__ eb1,
    const float* __restrict__ eb2, const float* __restrict__ eb3,
    const float* __restrict__ probs,  // [4][256][8]
    float* __restrict__ psums)        // [16][256][32]
{
    int bx = blockIdx.x;
    int b = bx >> 8, p = bx & 255;
    int py = p >> 4, px = p & 15;
    int tid = threadIdx.x;

    __shared__ float P[16][10][13];   // ping
    __shared__ float Q[16][10][13];   // pong
    __shared__ float se[4][8];
    __shared__ float sb[640];         // L0@0(128) L1@128 L2@256 L3@384(256)
    __shared__ int   ml[4][16];
    __shared__ int   mcnt[4];

    // zero halos of both buffers once (interior writes never touch them)
    for (int t = tid; t < 2 * 16 * 40; t += 256) {
        int buf = t >= 640; int t2 = t - buf * 640;
        int ch = t2 / 40, h = t2 % 40;
        int r, c;
        if (h < 12)      { r = 0; c = h; }
        else if (h < 24) { r = 9; c = h - 12; }
        else             { r = 1 + (h - 24) / 2; c = ((h - 24) & 1) ? 9 : 0; }
        if (buf) Q[ch][r][c] = 0.0f; else P[ch][r][c] = 0.0f;
    }
    // stage X (NCHW) into P channels 0..2
    for (int t = tid; t < 3 * 64; t += 256) {
        int cin = t >> 6, pix = t & 63, i = pix >> 3, j = pix & 7;
        P[cin][i + 1][j + 1] =
            X[((size_t)(b * 3 + cin) * 128 + (py * 8 + i)) * 128 + (px * 8 + j)];
    }
    if (tid < 32) se[tid >> 3][tid & 7] = probs[(tid >> 3) * 2048 + p * 8 + (tid & 7)];
    for (int t = tid; t < 640; t += 256) {
        float v;
        if (t < 128)      { int e = t >> 4, r = t & 15; v = (r < 8) ? eb0[e * 8 + r] : 0.0f; }
        else if (t < 256) v = eb1[t - 128];
        else if (t < 384) v = eb2[t - 256];
        else              v = eb3[t - 384];
        sb[t] = v;
    }
    if (tid < 4) {
        int lyr = tid;
        int MPEl = (lyr == 3) ? 2 : 1;
        int nact = 0;
        for (int e = 0; e < 8; ++e) {
            float pe = probs[lyr * 2048 + p * 8 + e];
            if (pe > 0.0f) { for (int u = 0; u < MPEl; ++u) ml[lyr][nact++] = e * MPEl + u; }
        }
        mcnt[lyr] = nact;
    }
    __syncthreads();

    int l = tid & 63, nt = tid >> 6;
    int n = nt * 16 + (l & 15);
    int pr = n >> 3, pc = n & 7;
    int lane4 = l >> 4, row4 = lane4 * 4;

    layer_run<3, 8, 16, 3, 1, false>(
        (const float (*)[10][13])P, (float*)Q, wA0, sb, se[0], ml[0], mcnt[0],
        l, lane4, pr, pc, row4, n);
    __syncthreads();
    layer_run<8, 16, 16, 8, 3, false>(
        (const float (*)[10][13])Q, (float*)P, wA1, sb + 128, se[1], ml[1], mcnt[1],
        l, lane4, pr, pc, row4, n);
    __syncthreads();
    layer_run<16, 16, 16, 16, 5, false>(
        (const float (*)[10][13])P, (float*)Q, wA2, sb + 256, se[2], ml[2], mcnt[2],
        l, lane4, pr, pc, row4, n);
    __syncthreads();
    layer_run<16, 32, 32, 16, 5, true>(
        (const float (*)[10][13])Q, (float*)P, wA3, sb + 384, se[3], ml[3], mcnt[3],
        l, lane4, pr, pc, row4, n);
    __syncthreads();

    // per-patch channel sums over 64 pixels -> psums[b][p][32]
    const float* Pf = (const float*)P;
    int cout = tid >> 3, seg = tid & 7;
    const float* q = Pf + cout * 64 + seg * 8;
    float s = 0.0f;
    #pragma unroll
    for (int kk = 0; kk < 8; ++kk) s += q[kk];
    s += __shfl_xor(s, 1); s += __shfl_xor(s, 2); s += __shfl_xor(s, 4);
    if (seg == 0) psums[(size_t)(b * 256 + p) * 32 + cout] = s;
}

// ---------------- FC: pool psums (2x2 patches per cell) + linear ------------
__global__ __launch_bounds__(256) void fc_kernel(
    const float* __restrict__ psums, const float* __restrict__ fcw,
    const float* __restrict__ fcb, float* __restrict__ out)
{
    int b = blockIdx.x;
    __shared__ float pooled[2048];
    for (int t = threadIdx.x; t < 2048; t += 256) {
        int c = t >> 6, cell = t & 63, oy = cell >> 3, ox = cell & 7;
        float s = 0.0f;
        #pragma unroll
        for (int dy = 0; dy < 2; ++dy)
            #pragma unroll
            for (int dx = 0; dx < 2; ++dx) {
                int p = (2 * oy + dy) * 16 + (2 * ox + dx);
                s += psums[(size_t)(b * 256 + p) * 32 + c];
            }
        pooled[t] = s * (1.0f / 256.0f);
    }
    __syncthreads();

    int wave = threadIdx.x >> 6, lane = threadIdx.x & 63;
    for (int cls = wave; cls < 100; cls += 4) {
        float a = 0.0f;
        #pragma unroll
        for (int r = 0; r < 32; ++r)
            a += pooled[r * 64 + lane] * fcw[(size_t)cls * 2048 + r * 64 + lane];
        #pragma unroll
        for (int off = 32; off > 0; off >>= 1) a += __shfl_down(a, off);
        if (lane == 0) out[b * 100 + cls] = a + fcb[cls];
    }
}

// ---------------- Launch ----------------------------------------------------
extern "C" void kernel_launch(void* const* d_in, const int* in_sizes, int n_in,
                              void* d_out, int out_size, void* d_ws, size_t ws_size,
                              hipStream_t stream) {
    const float* X = (const float*)d_in[0];
    const float* ew[4]; const float* eb[4];
    RouterArgs ra;
    for (int l = 0; l < 4; ++l) {
        ew[l]     = (const float*)d_in[1 + 6*l + 0];
        eb[l]     = (const float*)d_in[1 + 6*l + 1];
        ra.rw[l]  = (const float*)d_in[1 + 6*l + 2];
        ra.rb[l]  = (const float*)d_in[1 + 6*l + 3];
        ra.rlw[l] = (const float*)d_in[1 + 6*l + 4];
        ra.rlb[l] = (const float*)d_in[1 + 6*l + 5];
    }
    const float* fcw = (const float*)d_in[25];
    const float* fcb = (const float*)d_in[26];

    char* ws = (char*)d_ws;
    float* probs  = (float*)ws;                       // 4*2048 f  = 32 KB
    float* psums  = (float*)(ws + 32768);             // 16*256*32 f = 512 KB
    unsigned short* wA0 = (unsigned short*)(ws + 32768 + 524288);
    unsigned short* wA1 = wA0 + 4096;                 // 8*1*512
    unsigned short* wA2 = wA1 + 12288;                // 8*3*512
    unsigned short* wA3 = wA2 + 20480;                // 8*5*512 ; L3 = 16*5*512

    router_all<<<dim3(256, 4), 64, 0, stream>>>(ra, probs);
    prep_all<<<304, 256, 0, stream>>>(ew[0], ew[1], ew[2], ew[3], wA0, wA1, wA2, wA3);

    pce_fused<<<4096, 256, 0, stream>>>(X, wA0, wA1, wA2, wA3,
                                        eb[0], eb[1], eb[2], eb[3], probs, psums);

    fc_kernel<<<16, 256, 0, stream>>>(psums, fcw, fcb, (float*)d_out);
}

// Round 7
// 114.801 us; speedup vs baseline: 11.2849x; 1.2054x over previous
//
#include <hip/hip_runtime.h>
#include <math.h>

#define NE 8
#define PI_F 3.14159265358979323846f

typedef _Float16 half8 __attribute__((ext_vector_type(8)));
typedef float f32x4 __attribute__((ext_vector_type(4)));
typedef unsigned int uint2v __attribute__((ext_vector_type(2)));
typedef unsigned short u16x4 __attribute__((ext_vector_type(4)));

// Activation LDS layout: fp16, [y 0..9][x 0..9][c 0..23(pad)], u16 units
#define CP 24
#define ROWS 240        // 10 * CP
#define NELEM 2400      // 10*10*CP u16

__device__ __forceinline__ unsigned short f2h_bits(float v) {
    union { _Float16 h; unsigned short u; } cv;
    cv.h = (_Float16)v;
    return cv.u;
}

// ---------------- Setup: routers (blocks 0..255) + weight prep (256..575) ---
struct SetupArgs {
    const float* rw[4]; const float* rb[4]; const float* rlw[4]; const float* rlb[4];
    const float* ew[4];
    float* probs;
    unsigned short* w0; unsigned short* w1; unsigned short* w2; unsigned short* w3;
};

template<int CIN, int COUT_R, int COUT_P, int CSTR, int KS>
__device__ __forceinline__ void prep_one(
    const float* __restrict__ ew, unsigned short* __restrict__ wA, int idx)
{
    int j    = idx & 7;
    int lane = (idx >> 3) & 63;
    int t2   = idx >> 9;
    int ks   = t2 % KS;
    int mt   = t2 / KS;
    int m    = mt * 16 + (lane & 15);
    int e    = m / COUT_P, row = m % COUT_P;
    int k    = ks * 32 + (lane >> 4) * 8 + j;
    int cin  = k % CSTR, r = k / CSTR;
    float val = 0.0f;
    if (row < COUT_R && cin < CIN && r < 9)
        val = ew[((size_t)(e * COUT_R + row) * CIN + cin) * 9 + r];
    wA[idx] = f2h_bits(val);
}

__global__ __launch_bounds__(256) void setup_all(SetupArgs sa)
{
    int bx = blockIdx.x, tid = threadIdx.x;
    if (bx < 256) {
        int layer = tid >> 6, lane = tid & 63;
        const float* rw  = sa.rw[layer];  const float* rb  = sa.rb[layer];
        const float* rlw = sa.rlw[layer]; const float* rlb = sa.rlb[layer];
        int p = bx, py = p >> 4, px = p & 15;
        int i = lane >> 3, j = lane & 7;
        int y = py * 8 + i, x = px * 8 + j;

        float base0 = (x + 0.5f) / 128.0f;
        float base1 = (y + 0.5f) / 128.0f;
        float base2 = (j + 0.5f) / 8.0f;
        float base3 = (i + 0.5f) / 8.0f;

        float coord[52];
        coord[0] = base0; coord[1] = base1; coord[2] = base2; coord[3] = base3;
        int c = 4;
        #pragma unroll
        for (int f = 0; f < 6; ++f) {
            float w = PI_F * (float)(1 << f);
            coord[c+0] = sinf(w * base0); coord[c+1] = sinf(w * base1);
            coord[c+2] = sinf(w * base2); coord[c+3] = sinf(w * base3);
            coord[c+4] = cosf(w * base0); coord[c+5] = cosf(w * base1);
            coord[c+6] = cosf(w * base2); coord[c+7] = cosf(w * base3);
            c += 8;
        }
        float z[16];
        #pragma unroll
        for (int r = 0; r < 16; ++r) {
            float a = rb[r];
            #pragma unroll
            for (int cc = 0; cc < 52; ++cc) a += rw[r*52 + cc] * coord[cc];
            z[r] = fmaxf(a, 0.0f);
        }
        #pragma unroll
        for (int r = 0; r < 16; ++r) {
            float v = z[r];
            #pragma unroll
            for (int off = 32; off > 0; off >>= 1) v += __shfl_xor(v, off);
            z[r] = v * (1.0f / 64.0f);
        }
        int e = lane & 7;
        float logit = rlb[e];
        #pragma unroll
        for (int r = 0; r < 16; ++r) logit += rlw[e*16 + r] * z[r];
        float m = logit;
        #pragma unroll
        for (int off = 4; off > 0; off >>= 1) m = fmaxf(m, __shfl_xor(m, off));
        float ex = expf(logit - m);
        float s = ex;
        #pragma unroll
        for (int off = 4; off > 0; off >>= 1) s += __shfl_xor(s, off);
        float pr = ex / s;
        pr = (pr >= 0.05f) ? pr : 0.0f;
        float s2 = pr;
        #pragma unroll
        for (int off = 4; off > 0; off >>= 1) s2 += __shfl_xor(s2, off);
        pr = pr / (s2 + 1e-9f);
        if (lane < 8) sa.probs[layer * 2048 + p * 8 + lane] = pr;
    } else {
        int idx = (bx - 256) * 256 + tid;
        if (idx < 8192)       prep_one<3, 8, 16, 4, 2>(sa.ew[0], sa.w0, idx);
        else if (idx < 20480) prep_one<8, 16, 16, 8, 3>(sa.ew[1], sa.w1, idx - 8192);
        else if (idx < 40960) prep_one<16, 16, 16, 16, 5>(sa.ew[2], sa.w2, idx - 20480);
        else if (idx < 81920) prep_one<16, 32, 32, 16, 5>(sa.ew[3], sa.w3, idx - 40960);
    }
}

// ---------------- One layer inside the fused kernel -------------------------
// B reads are centered at (pr,pc): halo base = pr*ROWS + pc*CP (image rows
// pr-1..pr+1). Writes land at interior halo coords (1+pr,1+pc).
template<int KS, int CSTR, int MPE, bool LAST>
__device__ __forceinline__ void layer_run(
    const unsigned short* ain, unsigned short* aout,
    const unsigned short* __restrict__ wA,
    const float* sbL, const float* seL, const int* mlL, int mc,
    int l, int lane4, int pr, int pc, int row4, float (*ps)[32], int nt)
{
    const int rbase = pr * ROWS + pc * CP;              // read base (centered)
    const int wbase = (1 + pr) * ROWS + (1 + pc) * CP;  // write base (interior)

    // ---- B fragments: contiguous fp16 ds_reads, no repack ----
    half8 Bh[KS];
    if (CSTR == 16) {
        int cb = (lane4 & 1) * 8;
        int rb = lane4 >> 1;
        #pragma unroll
        for (int ks = 0; ks < KS; ++ks) {
            int r0 = 2 * ks, r1 = 2 * ks + 1;
            int o0 = ((r0 / 3) * 10 + (r0 % 3)) * CP;
            int o1 = ((r1 / 3) * 10 + (r1 % 3)) * CP;
            int off = rb ? o1 : o0;
            half8 v{};
            if (2 * ks + rb < 9) v = *(const half8*)(ain + rbase + off + cb);
            Bh[ks] = v;
        }
    } else if (CSTR == 8) {
        #pragma unroll
        for (int ks = 0; ks < KS; ++ks) {
            int r = 4 * ks + lane4;
            int dy = (r * 11) >> 5, dx = r - 3 * dy;
            int off = (dy * 10 + dx) * CP;
            half8 v{};
            if (r < 9) v = *(const half8*)(ain + rbase + off);
            Bh[ks] = v;
        }
    } else { // CSTR == 4
        #pragma unroll
        for (int ks = 0; ks < KS; ++ks) {
            union { half8 v; uint2v u2[2]; } bb;
            #pragma unroll
            for (int h = 0; h < 2; ++h) {
                int r = 8 * ks + 2 * lane4 + h;
                int dy = (r * 11) >> 5, dx = r - 3 * dy;
                int off = (dy * 10 + dx) * CP;
                uint2v u{};
                if (r < 9) u = *(const uint2v*)(ain + rbase + off);
                bb.u2[h] = u;
            }
            Bh[ks] = bb.v;
        }
    }

    // ---- mtile loop: bias-in-C MFMA, fmaf combine ----
    f32x4 acc0 = {0.f, 0.f, 0.f, 0.f};
    f32x4 acc1 = {0.f, 0.f, 0.f, 0.f};
    const unsigned short* apl = wA + l * 8;
    for (int mi = 0; mi < mc; ++mi) {
        int mt = mlL[mi];
        const unsigned short* ap = apl + (size_t)mt * (KS * 512);
        f32x4 ct = *(const f32x4*)&sbL[mt * 16 + row4];
        #pragma unroll
        for (int ks = 0; ks < KS; ++ks) {
            half8 a = *(const half8*)(ap + ks * 512);
            ct = __builtin_amdgcn_mfma_f32_16x16x32_f16(a, Bh[ks], ct, 0, 0, 0);
        }
        float pe = seL[(MPE == 2) ? (mt >> 1) : mt];
        #pragma unroll
        for (int j = 0; j < 4; ++j) {
            float v = fmaxf(ct[j], 0.0f);
            if (MPE == 2 && (mt & 1)) acc1[j] = fmaf(v, pe, acc1[j]);
            else                      acc0[j] = fmaf(v, pe, acc0[j]);
        }
    }

    if (!LAST) {
        union { _Float16 h[4]; u16x4 u; } o;
        #pragma unroll
        for (int j = 0; j < 4; ++j) o.h[j] = (_Float16)acc0[j];
        *(u16x4*)(aout + wbase + row4) = o.u;
    } else {
        // channel sums over the wave's 16 pixels via shfl, stash per-wave
        #pragma unroll
        for (int j = 0; j < 4; ++j) {
            float s0 = acc0[j], s1 = acc1[j];
            #pragma unroll
            for (int off = 1; off < 16; off <<= 1) {
                s0 += __shfl_xor(s0, off);
                s1 += __shfl_xor(s1, off);
            }
            if ((l & 15) == 0) {
                ps[nt][row4 + j] = s0;
                ps[nt][16 + row4 + j] = s1;
            }
        }
    }
}

// ---------------- Fused all-4-layer conv + per-patch channel sums -----------
__global__ __launch_bounds__(256, 8) void pce_fused(
    const float* __restrict__ X,
    const unsigned short* __restrict__ wA0, const unsigned short* __restrict__ wA1,
    const unsigned short* __restrict__ wA2, const unsigned short* __restrict__ wA3,
    const float* __restrict__ eb0, const float* __restrict__ eb1,
    const float* __restrict__ eb2, const float* __restrict__ eb3,
    const float* __restrict__ probs,  // [4][256][8]
    float* __restrict__ psums)        // [16][256][32]
{
    int bx = blockIdx.x;
    int b = bx >> 8, p = bx & 255;
    int py = p >> 4, px = p & 15;
    int tid = threadIdx.x;

    __shared__ unsigned short A0[NELEM];
    __shared__ unsigned short A1[NELEM];
    __shared__ alignas(16) float sb[640];
    __shared__ float se[4][8];
    __shared__ int   ml[4][16];
    __shared__ int   mcnt[4];
    __shared__ float ps[4][32];

    for (int t = tid; t < NELEM / 2; t += 256) {
        ((unsigned int*)A0)[t] = 0u;
        ((unsigned int*)A1)[t] = 0u;
    }
    for (int t = tid; t < 192; t += 256) {
        int cin = t >> 6, pix = t & 63, i = pix >> 3, j = pix & 7;
        float v = X[((size_t)(b * 3 + cin) * 128 + (py * 8 + i)) * 128 + (px * 8 + j)];
        A0[(1 + i) * ROWS + (1 + j) * CP + cin] = f2h_bits(v);
    }
    if (tid < 32) se[tid >> 3][tid & 7] = probs[(tid >> 3) * 2048 + p * 8 + (tid & 7)];
    for (int t = tid; t < 640; t += 256) {
        float v;
        if (t < 128)      { int e = t >> 4, r = t & 15; v = (r < 8) ? eb0[e * 8 + r] : 0.0f; }
        else if (t < 256) v = eb1[t - 128];
        else if (t < 384) v = eb2[t - 256];
        else              v = eb3[t - 384];
        sb[t] = v;
    }
    if (tid < 4) {
        int lyr = tid;
        int MPEl = (lyr == 3) ? 2 : 1;
        int nact = 0;
        for (int e = 0; e < 8; ++e) {
            float pe = probs[lyr * 2048 + p * 8 + e];
            if (pe > 0.0f) { for (int u = 0; u < MPEl; ++u) ml[lyr][nact++] = e * MPEl + u; }
        }
        mcnt[lyr] = nact;
    }
    __syncthreads();

    int l = tid & 63, nt = tid >> 6;
    int n = nt * 16 + (l & 15);
    int pr = n >> 3, pc = n & 7;
    int lane4 = l >> 4, row4 = lane4 * 4;

    layer_run<2, 4, 1, false>(A0, A1, wA0, sb,       se[0], ml[0], mcnt[0], l, lane4, pr, pc, row4, nullptr, nt);
    __syncthreads();
    layer_run<3, 8, 1, false>(A1, A0, wA1, sb + 128, se[1], ml[1], mcnt[1], l, lane4, pr, pc, row4, nullptr, nt);
    __syncthreads();
    layer_run<5, 16, 1, false>(A0, A1, wA2, sb + 256, se[2], ml[2], mcnt[2], l, lane4, pr, pc, row4, nullptr, nt);
    __syncthreads();
    layer_run<5, 16, 2, true>(A1, A0, wA3, sb + 384, se[3], ml[3], mcnt[3], l, lane4, pr, pc, row4, ps, nt);
    __syncthreads();

    if (tid < 32) {
        float s = ps[0][tid] + ps[1][tid] + ps[2][tid] + ps[3][tid];
        psums[(size_t)(b * 256 + p) * 32 + tid] = s;
    }
}

// ---------------- FC: pool psums (2x2 patches per cell) + linear ------------
__global__ __launch_bounds__(256) void fc_kernel(
    const float* __restrict__ psums, const float* __restrict__ fcw,
    const float* __restrict__ fcb, float* __restrict__ out)
{
    int b = blockIdx.x;
    __shared__ float pooled[2048];
    for (int t = threadIdx.x; t < 2048; t += 256) {
        int c = t >> 6, cell = t & 63, oy = cell >> 3, ox = cell & 7;
        float s = 0.0f;
        #pragma unroll
        for (int dy = 0; dy < 2; ++dy)
            #pragma unroll
            for (int dx = 0; dx < 2; ++dx) {
                int pp = (2 * oy + dy) * 16 + (2 * ox + dx);
                s += psums[(size_t)(b * 256 + pp) * 32 + c];
            }
        pooled[t] = s * (1.0f / 256.0f);
    }
    __syncthreads();

    int wave = threadIdx.x >> 6, lane = threadIdx.x & 63;
    for (int cls = wave; cls < 100; cls += 4) {
        float a = 0.0f;
        #pragma unroll
        for (int r = 0; r < 32; ++r)
            a += pooled[r * 64 + lane] * fcw[(size_t)cls * 2048 + r * 64 + lane];
        #pragma unroll
        for (int off = 32; off > 0; off >>= 1) a += __shfl_down(a, off);
        if (lane == 0) out[b * 100 + cls] = a + fcb[cls];
    }
}

// ---------------- Launch ----------------------------------------------------
extern "C" void kernel_launch(void* const* d_in, const int* in_sizes, int n_in,
                              void* d_out, int out_size, void* d_ws, size_t ws_size,
                              hipStream_t stream) {
    const float* X = (const float*)d_in[0];
    const float* eb[4];
    SetupArgs sa;
    for (int l = 0; l < 4; ++l) {
        sa.ew[l]  = (const float*)d_in[1 + 6*l + 0];
        eb[l]     = (const float*)d_in[1 + 6*l + 1];
        sa.rw[l]  = (const float*)d_in[1 + 6*l + 2];
        sa.rb[l]  = (const float*)d_in[1 + 6*l + 3];
        sa.rlw[l] = (const float*)d_in[1 + 6*l + 4];
        sa.rlb[l] = (const float*)d_in[1 + 6*l + 5];
    }
    const float* fcw = (const float*)d_in[25];
    const float* fcb = (const float*)d_in[26];

    char* ws = (char*)d_ws;
    float* probs  = (float*)ws;                       // 32 KB
    float* psums  = (float*)(ws + 32768);             // 512 KB
    unsigned short* wA0 = (unsigned short*)(ws + 32768 + 524288);
    unsigned short* wA1 = wA0 + 8192;
    unsigned short* wA2 = wA1 + 12288;
    unsigned short* wA3 = wA2 + 20480;                // + 40960

    sa.probs = probs; sa.w0 = wA0; sa.w1 = wA1; sa.w2 = wA2; sa.w3 = wA3;

    setup_all<<<576, 256, 0, stream>>>(sa);
    pce_fused<<<4096, 256, 0, stream>>>(X, wA0, wA1, wA2, wA3,
                                        eb[0], eb[1], eb[2], eb[3], probs, psums);
    fc_kernel<<<16, 256, 0, stream>>>(psums, fcw, fcb, (float*)d_out);
}